// Round 7
// baseline (45.733 us; speedup 1.0000x reference)
//
#include <hip/hip_runtime.h>

// PS-RoIAlign forward, fp32 — round 7: LDS-staged plane gather.
//
// Diagnosis after rounds 4-6 (all flat at ~30 µs): the binding resource is
// random 64B-line traffic through L1-miss/L2/LLC (~224 MB at ~7.5 TB/s);
// line reuse is only ~1.35x so no cache-blocking can fix it. Restructure:
//   K1 bin:       bucket rois by batch (exact, deterministic, no atomics)
//   K2 gather:    1 block per (batch, channel) plane: stream 40 KB plane ->
//                 LDS (coalesced float4), gather bilinear samples from LDS,
//                 write outT[c][slot] coalesced
//   K3 transpose: outT[490][2048] + slot->k map -> out[k][490], tiled LDS
// Sequentializes all DRAM/LLC traffic (157 MB streamed once) and moves the
// randomness into LDS where it is ~free.
//
// input [8,490,100,100] fp32, rois [2048,5], out [2048,490]

#define PSR_N  8
#define PSR_C  490
#define PSR_H  100
#define PSR_W  100
#define PSR_HW 10000
#define PSR_K  2048
#define PSR_SC 0.0625f

typedef float f4v __attribute__((ext_vector_type(4)));
typedef float f2v __attribute__((ext_vector_type(2)));

// ws layout: ints [0,2048) slotk ; [2048,2056) base[b] ; [2056,2064) cnt[b]
// outT (float [490][2048]) at byte offset 8448 (16B aligned)
#define WS_META_BASE 2048
#define WS_META_CNT  2056
#define WS_OUTT_BYTE 8448
#define WS_NEEDED    (WS_OUTT_BYTE + (size_t)PSR_C * PSR_K * 4)

// ---------------- K1: bin rois by batch (1 block, 256 threads) -------------
__global__ __launch_bounds__(256) void psr_bin(const float* __restrict__ rois,
                                               int* __restrict__ wsI)
{
    __shared__ int cnt8[8 * 256];   // [b][t] counts, then exclusive prefixes
    __shared__ int rowtot[8];
    __shared__ int rowbase[8];

    const int t    = threadIdx.x;
    const int lane = t & 63;
    const int w    = t >> 6;

    int bi[8];
#pragma unroll
    for (int j = 0; j < 8; ++j) bi[j] = (int)rois[(t * 8 + j) * 5];

#pragma unroll
    for (int b = 0; b < 8; ++b) {
        int s = 0;
#pragma unroll
        for (int j = 0; j < 8; ++j) s += (bi[j] == b) ? 1 : 0;
        cnt8[b * 256 + t] = s;
    }
    __syncthreads();

    // per-row (batch) exclusive prefix over 256 columns; wave w: rows w, w+4
#pragma unroll
    for (int rb = 0; rb < 2; ++rb) {
        const int b = w + rb * 4;
        int v[4], e[4];
#pragma unroll
        for (int q = 0; q < 4; ++q) v[q] = cnt8[b * 256 + lane * 4 + q];
        e[0] = 0; e[1] = v[0]; e[2] = v[0] + v[1]; e[3] = v[0] + v[1] + v[2];
        const int lanesum = e[3] + v[3];
        int sc = lanesum;
#pragma unroll
        for (int d = 1; d < 64; d <<= 1) {
            int o = __shfl_up(sc, d, 64);
            if (lane >= d) sc += o;
        }
        const int laneexcl = sc - lanesum;
#pragma unroll
        for (int q = 0; q < 4; ++q)
            cnt8[b * 256 + lane * 4 + q] = laneexcl + e[q];
        if (lane == 63) rowtot[b] = sc;
    }
    __syncthreads();

    if (t == 0) {
        int s = 0;
        for (int b = 0; b < 8; ++b) { rowbase[b] = s; s += rowtot[b]; }
    }
    __syncthreads();

    if (t < 8) {
        wsI[WS_META_BASE + t] = rowbase[t];
        wsI[WS_META_CNT + t]  = rowtot[t];
    }

#pragma unroll
    for (int j = 0; j < 8; ++j) {
        const int b = bi[j];
        int before = 0;
#pragma unroll
        for (int j2 = 0; j2 < j; ++j2) before += (bi[j2] == b) ? 1 : 0;
        wsI[rowbase[b] + cnt8[b * 256 + t] + before] = t * 8 + j;
    }
}

// ---------------- K2: plane gather (3920 blocks, 256 threads) --------------
__global__ __launch_bounds__(256) void psr_gather(const float* __restrict__ input,
                                                  const float* __restrict__ rois,
                                                  const int* __restrict__ wsI,
                                                  float* __restrict__ outT)
{
    __shared__ f4v plane4[PSR_HW / 4];          // 40 KB -> 4 blocks/CU
    float* plane = (float*)plane4;

    const int tid = threadIdx.x;
    const int b   = blockIdx.x & 7;
    const int c   = blockIdx.x >> 3;            // 0..489

    // stream the whole (b,c) plane into LDS, coalesced float4
    const f4v* src = (const f4v*)(input + ((size_t)b * PSR_C + c) * PSR_HW);
#pragma unroll
    for (int i = 0; i < 10; ++i) {
        const int idx = tid + i * 256;
        if (idx < PSR_HW / 4) plane4[idx] = src[idx];
    }
    __syncthreads();

    const int base = wsI[WS_META_BASE + b];
    const int cnt  = wsI[WS_META_CNT + b];

    const int s49 = c % 49;
    const int ph  = s49 / 7;
    const int pw  = s49 - ph * 7;

    for (int i = tid; i < cnt; i += 256) {
        const int k = wsI[base + i];
        const float* r = rois + k * 5;
        const float sw = r[1] * PSR_SC - 0.5f;
        const float sh = r[2] * PSR_SC - 0.5f;
        const float ew = r[3] * PSR_SC - 0.5f;
        const float eh = r[4] * PSR_SC - 0.5f;
        const float bin_w = fmaxf(ew - sw, 0.1f) * (1.0f / 7.0f);
        const float bin_h = fmaxf(eh - sh, 0.1f) * (1.0f / 7.0f);

        int   yl[2], yh2[2], xl[2], xh2[2];
        float fy[2], fx[2], my[2], mx[2];
#pragma unroll
        for (int ii = 0; ii < 2; ++ii) {
            const float off = (ii + 0.5f) * 0.5f;

            float y = sh + ((float)ph + off) * bin_h;
            my[ii] = (y >= -1.0f && y <= (float)PSR_H) ? 1.0f : 0.0f;
            float cy = fmaxf(y, 0.0f);
            int lo = min((int)cy, PSR_H - 1);
            yl[ii]  = lo;
            yh2[ii] = min(lo + 1, PSR_H - 1);
            if (lo >= PSR_H - 1) cy = (float)lo;
            fy[ii] = cy - (float)lo;

            float x = sw + ((float)pw + off) * bin_w;
            mx[ii] = (x >= -1.0f && x <= (float)PSR_W) ? 1.0f : 0.0f;
            float cx = fmaxf(x, 0.0f);
            int lox = min((int)cx, PSR_W - 1);
            xl[ii]  = lox;
            xh2[ii] = min(lox + 1, PSR_W - 1);
            if (lox >= PSR_W - 1) cx = (float)lox;
            fx[ii] = cx - (float)lox;
        }

        float acc = 0.0f;
#pragma unroll
        for (int iy = 0; iy < 2; ++iy) {
            const float ly = fy[iy], hy = 1.0f - fy[iy];
            const int r0 = yl[iy] * PSR_W, r1 = yh2[iy] * PSR_W;
#pragma unroll
            for (int ix = 0; ix < 2; ++ix) {
                const float lx = fx[ix], hx = 1.0f - fx[ix];
                const float v = plane[r0 + xl[ix]]  * (hy * hx)
                              + plane[r0 + xh2[ix]] * (hy * lx)
                              + plane[r1 + xl[ix]]  * (ly * hx)
                              + plane[r1 + xh2[ix]] * (ly * lx);
                acc += (my[iy] * mx[ix]) * v;
            }
        }
        outT[(size_t)c * PSR_K + base + i] = acc * 0.25f;   // coalesced
    }
}

// ---------------- K3: transpose outT -> out (256 blocks) -------------------
__global__ __launch_bounds__(256) void psr_transpose(const float* __restrict__ outT,
                                                     const int* __restrict__ wsI,
                                                     float* __restrict__ out)
{
    __shared__ float tile[64][65];
    const int t  = threadIdx.x;
    const int c0 = (blockIdx.x & 7) * 64;      // channel tile (8 tiles)
    const int s0 = (blockIdx.x >> 3) * 64;     // slot tile (32 tiles)

    const int sj = t & 63;
    const int rr = t >> 6;
#pragma unroll
    for (int i = 0; i < 16; ++i) {
        const int r = rr + i * 4;              // rows 0..63
        const int c = c0 + r;
        if (c < PSR_C) tile[r][sj] = outT[(size_t)c * PSR_K + s0 + sj];
    }
    __syncthreads();

    const int j = t >> 2;                      // slot within tile
    const int q = t & 3;
    const int k = wsI[s0 + j];                 // slot -> roi
    float* orow = out + (size_t)k * PSR_C;
#pragma unroll
    for (int it = 0; it < 8; ++it) {
        const int pj = q + it * 4;             // channel pair 0..31
        const int c  = c0 + pj * 2;
        if (c < PSR_C) {
            f2v v; v.x = tile[pj * 2][j]; v.y = tile[pj * 2 + 1][j];
            *(f2v*)(orow + c) = v;             // 8B-aligned (c even)
        }
    }
}

// ---------------- fallback: round-5 kernel (if ws too small) ---------------
typedef float f4a __attribute__((ext_vector_type(4), aligned(4)));
__device__ __forceinline__ f4a ld4u(const float* p) { return *(const f4a*)p; }
__device__ __forceinline__ float sel3(float a0, float a1, float a2, int e) {
    float r = (e == 1) ? a1 : a0;
    return (e == 2) ? a2 : r;
}

__global__ __launch_bounds__(256) void psr_fallback(
    const float* __restrict__ input,
    const float* __restrict__ rois,
    float* __restrict__ out)
{
    const int tid  = threadIdx.x;
    const int xcd  = blockIdx.x & 7;
    const int slot = blockIdx.x >> 3;
    const int j    = slot >> 3;
    const int rb   = slot & 7;
    const int k    = rb * 256 + tid;
    const int cb   = xcd * 64 + j * 4;
    if (cb >= PSR_C) return;

    f4a rv4 = ld4u(rois + k * 5);
    const int   b  = (int)rv4.x;
    const float sw = rv4.y * PSR_SC - 0.5f;
    const float sh = rv4.z * PSR_SC - 0.5f;
    const float ew = rv4.w * PSR_SC - 0.5f;
    const float eh = rois[k * 5 + 4] * PSR_SC - 0.5f;
    const float bin_w = fmaxf(ew - sw, 0.1f) * (1.0f / 7.0f);
    const float bin_h = fmaxf(eh - sh, 0.1f) * (1.0f / 7.0f);
    const float* bb = input + (size_t)b * (PSR_C * PSR_HW);

    f4a   w[4][4];
    float wx[4][4], wy[4][4];
    int   e0a[4], e1a[4], da[4], o0a[4], o2a[4];

#pragma unroll
    for (int g = 0; g < 4; ++g) {
        const int c  = cb + g;
        const int cv = (c < PSR_C);
        const int ca = cv ? c : (PSR_C - 1);
        const int s49 = ca % 49;
        const int ph  = s49 / 7;
        const int pw  = s49 - ph * 7;
        int yb[2], xb[2];
#pragma unroll
        for (int i = 0; i < 2; ++i) {
            const float off = (i + 0.5f) * 0.5f;
            float y  = sh + ((float)ph + off) * bin_h;
            float myv = (y >= -1.0f && y <= (float)PSR_H) ? 0.25f : 0.0f;
            if (!cv) myv = 0.0f;
            float cy = fmaxf(y, 0.0f);
            int lo = min((int)cy, PSR_H - 1);
            float fr = cy - (float)lo;
            if (lo >= PSR_H - 1) { yb[i] = PSR_H - 2; wy[g][2*i] = 0.0f;              wy[g][2*i+1] = myv;      }
            else                 { yb[i] = lo;        wy[g][2*i] = myv * (1.0f - fr); wy[g][2*i+1] = myv * fr; }
            float x  = sw + ((float)pw + off) * bin_w;
            float mxv = (x >= -1.0f && x <= (float)PSR_W) ? 1.0f : 0.0f;
            float cx = fmaxf(x, 0.0f);
            int lox = min((int)cx, PSR_W - 1);
            float frx = cx - (float)lox;
            if (lox >= PSR_W - 1) { xb[i] = PSR_W - 2; wx[g][2*i] = 0.0f;               wx[g][2*i+1] = mxv;       }
            else                  { xb[i] = lox;       wx[g][2*i] = mxv * (1.0f - frx); wx[g][2*i+1] = mxv * frx; }
        }
        const int xs = min(xb[0], PSR_W - 4);
        const int d  = yb[1] - yb[0];
        const int o0 = ca * PSR_HW + yb[0] * PSR_W + xs;
        const int o2 = ca * PSR_HW + yb[1] * PSR_W + xs;
        e0a[g] = xb[0] - xs; e1a[g] = xb[1] - xs; da[g] = d; o0a[g] = o0; o2a[g] = o2;
        w[g][0] = ld4u(bb + o0);
        w[g][1] = ld4u(bb + o0 + PSR_W);
        if (d >= 2) w[g][2] = ld4u(bb + o2);
        if (d >= 1) w[g][3] = ld4u(bb + o2 + PSR_W);
    }

    float acc[4];
#pragma unroll
    for (int g = 0; g < 4; ++g) {
        const int e0 = e0a[g], e1 = e1a[g], d = da[g];
        const bool far = (e1 > 2);
        f4a w0 = w[g][0], w1 = w[g][1];
        f4a w2 = (d == 0) ? w0 : ((d == 1) ? w1 : w[g][2]);
        f4a w3 = (d == 0) ? w1 : w[g][3];
        float ex[4] = {0.f, 0.f, 0.f, 0.f};
        if (far) {
            ex[0] = bb[o0a[g] + 4];
            ex[1] = bb[o0a[g] + PSR_W + 4];
            ex[2] = bb[o2a[g] + 4];
            ex[3] = bb[o2a[g] + PSR_W + 4];
        }
        const f4a wrow[4] = { w0, w1, w2, w3 };
        float rsum[4];
#pragma unroll
        for (int rr2 = 0; rr2 < 4; ++rr2) {
            const f4a ww = wrow[rr2];
            float s0l = sel3(ww.x, ww.y, ww.z, e0);
            float s0h = sel3(ww.y, ww.z, ww.w, e0);
            float s1l = far ? ww.w    : sel3(ww.x, ww.y, ww.z, e1);
            float s1h = far ? ex[rr2] : sel3(ww.y, ww.z, ww.w, e1);
            rsum[rr2] = (s0l * wx[g][0] + s0h * wx[g][1])
                      + (s1l * wx[g][2] + s1h * wx[g][3]);
        }
        acc[g] = wy[g][0] * rsum[0] + wy[g][1] * rsum[1]
               + wy[g][2] * rsum[2] + wy[g][3] * rsum[3];
    }

    float* o = out + (size_t)k * PSR_C + cb;
    f2v a { acc[0], acc[1] };
    *(f2v*)o = a;
    if (cb + 4 <= PSR_C) {
        f2v c2 { acc[2], acc[3] };
        *(f2v*)(o + 2) = c2;
    }
}

extern "C" void kernel_launch(void* const* d_in, const int* in_sizes, int n_in,
                              void* d_out, int out_size, void* d_ws, size_t ws_size,
                              hipStream_t stream) {
    const float* input = (const float*)d_in[0];
    const float* rois  = (const float*)d_in[1];
    float* out = (float*)d_out;

    if (ws_size >= WS_NEEDED + 1024) {
        int*   wsI  = (int*)d_ws;
        float* outT = (float*)((char*)d_ws + WS_OUTT_BYTE);
        psr_bin<<<1, 256, 0, stream>>>(rois, wsI);
        psr_gather<<<PSR_N * PSR_C, 256, 0, stream>>>(input, rois, wsI, outT);
        psr_transpose<<<256, 256, 0, stream>>>(outT, wsI, out);
    } else {
        psr_fallback<<<1024, 256, 0, stream>>>(input, rois, out);
    }
}

// Round 8
// 28.980 us; speedup vs baseline: 1.5781x; 1.5781x over previous
//
#include <hip/hip_runtime.h>

// PS-RoIAlign forward, fp32 — round 8: revert to round-5 kernel (best: 29.19 µs).
//
// Round-7's LDS-staged restream was 1.56x slower (45.7 µs) — staging the
// whole input through LDS serializes on the plane-load drain and adds
// transpose traffic, while the random-gather path was already moving
// near-compulsory bytes. Plateau evidence (rounds 4-7): request cut,
// 4x MLP, temporal phasing, full restream — all flat or worse at ~29-30 µs.
// ~224 MB line-granular traffic at ~7.6 TB/s effective L2-miss/LLC rate
// = 29 µs: structural floor for a ~1x-reuse gather over an LLC-resident set.
//
// Structure: 1024 blocks x 256 threads; thread owns roi k x 4 consecutive
// channels; one 16B window per bilinear row (rows 2/3 predicated on
// y-sample distinctness); rare far-x lanes take scalar fixups; validity
// masks and the /4 mean folded into weights; 2x8B staged stores.
//
// input [8,490,100,100] fp32, rois [2048,5], out [2048,490]

#define PSR_C  490
#define PSR_H  100
#define PSR_W  100
#define PSR_HW (PSR_H * PSR_W)
#define PSR_SC 0.0625f

typedef float f4v __attribute__((ext_vector_type(4), aligned(4)));
typedef float f2v __attribute__((ext_vector_type(2), aligned(4)));

__device__ __forceinline__ f4v ld4(const float* p) { return *(const f4v*)p; }

// select element e (0..2) / e+1 from a 4-wide window
__device__ __forceinline__ float sel3(float a0, float a1, float a2, int e) {
    float r = (e == 1) ? a1 : a0;
    return (e == 2) ? a2 : r;
}

__global__ __launch_bounds__(256) void PSRoIAlign_72069551227028_kernel(
    const float* __restrict__ input,
    const float* __restrict__ rois,
    float* __restrict__ out)
{
    const int tid  = threadIdx.x;
    const int xcd  = blockIdx.x & 7;
    const int slot = blockIdx.x >> 3;   // 0..127
    const int j    = slot >> 3;         // 0..15 channel-quad within XCD chunk
    const int rb   = slot & 7;          // 0..7  roi block
    const int k    = rb * 256 + tid;    // 0..2047
    const int cb   = xcd * 64 + j * 4;  // first of this thread's 4 channels
    if (cb >= PSR_C) return;            // uniform per block

    // ---- per-roi params ----
    f4v  rv4 = ld4(rois + k * 5);
    const int   b  = (int)rv4.x;
    const float sw = rv4.y * PSR_SC - 0.5f;
    const float sh = rv4.z * PSR_SC - 0.5f;
    const float ew = rv4.w * PSR_SC - 0.5f;
    const float eh = rois[k * 5 + 4] * PSR_SC - 0.5f;
    const float bin_w = fmaxf(ew - sw, 0.1f) * (1.0f / 7.0f);
    const float bin_h = fmaxf(eh - sh, 0.1f) * (1.0f / 7.0f);

    const float* bb = input + (size_t)b * (PSR_C * PSR_HW);

    // ---- phase 1: params + issue all loads ----
    f4v   w[4][4];                 // [g][row]; rows 2,3 conditionally loaded
    float wx[4][4], wy[4][4];      // x {l0,h0,l1,h1} (mskx folded); y likewise (msky*0.25 folded)
    int   e0a[4], e1a[4], da[4];
    int   o0a[4], o2a[4];          // window row offsets from bb

#pragma unroll
    for (int g = 0; g < 4; ++g) {
        const int c  = cb + g;
        const int cv = (c < PSR_C);
        const int ca = cv ? c : (PSR_C - 1);   // safe addressing for tail quad
        const int s49 = ca % 49;
        const int ph  = s49 / 7;
        const int pw  = s49 - ph * 7;

        int yb[2], xb[2];
#pragma unroll
        for (int i = 0; i < 2; ++i) {
            const float off = (i + 0.5f) * 0.5f;

            float y  = sh + ((float)ph + off) * bin_h;
            float my = (y >= -1.0f && y <= (float)PSR_H) ? 0.25f : 0.0f;  // fold mean/4
            if (!cv) my = 0.0f;
            float cy = fmaxf(y, 0.0f);
            int lo = min((int)cy, PSR_H - 1);
            float fr = cy - (float)lo;
            if (lo >= PSR_H - 1) { yb[i] = PSR_H - 2; wy[g][2*i] = 0.0f;             wy[g][2*i+1] = my;      }
            else                 { yb[i] = lo;        wy[g][2*i] = my * (1.0f - fr); wy[g][2*i+1] = my * fr; }

            float x  = sw + ((float)pw + off) * bin_w;
            float mx = (x >= -1.0f && x <= (float)PSR_W) ? 1.0f : 0.0f;
            float cx = fmaxf(x, 0.0f);
            int lox = min((int)cx, PSR_W - 1);
            float frx = cx - (float)lox;
            if (lox >= PSR_W - 1) { xb[i] = PSR_W - 2; wx[g][2*i] = 0.0f;              wx[g][2*i+1] = mx;       }
            else                  { xb[i] = lox;       wx[g][2*i] = mx * (1.0f - frx); wx[g][2*i+1] = mx * frx; }
        }

        const int xs = min(xb[0], PSR_W - 4);
        const int d  = yb[1] - yb[0];
        const int o0 = ca * PSR_HW + yb[0] * PSR_W + xs;
        const int o2 = ca * PSR_HW + yb[1] * PSR_W + xs;
        e0a[g] = xb[0] - xs;     // 0..2
        e1a[g] = xb[1] - xs;     // 0..3 (3 rare)
        da[g]  = d;
        o0a[g] = o0;
        o2a[g] = o2;

        w[g][0] = ld4(bb + o0);
        w[g][1] = ld4(bb + o0 + PSR_W);
        if (d >= 2) w[g][2] = ld4(bb + o2);            // exec-masked: row yb1
        if (d >= 1) w[g][3] = ld4(bb + o2 + PSR_W);    // exec-masked: row yb1+1
    }

    // ---- phase 2: consume ----
    float acc[4];
#pragma unroll
    for (int g = 0; g < 4; ++g) {
        const int e0 = e0a[g], e1 = e1a[g], d = da[g];
        const bool far = (e1 > 2);

        f4v w0 = w[g][0], w1 = w[g][1];
        f4v w2 = (d == 0) ? w0 : ((d == 1) ? w1 : w[g][2]);
        f4v w3 = (d == 0) ? w1 : w[g][3];

        float ex[4] = {0.f, 0.f, 0.f, 0.f};
        if (far) {                       // rare; one scalar per row at xs+4
            ex[0] = bb[o0a[g] + 4];
            ex[1] = bb[o0a[g] + PSR_W + 4];
            ex[2] = bb[o2a[g] + 4];
            ex[3] = bb[o2a[g] + PSR_W + 4];
        }

        const f4v wrow[4] = { w0, w1, w2, w3 };
        float rsum[4];                   // wy-weighted row sums
#pragma unroll
        for (int rr = 0; rr < 4; ++rr) {
            const f4v ww = wrow[rr];
            float s0l = sel3(ww.x, ww.y, ww.z, e0);
            float s0h = sel3(ww.y, ww.z, ww.w, e0);
            float s1l = far ? ww.w   : sel3(ww.x, ww.y, ww.z, e1);
            float s1h = far ? ex[rr] : sel3(ww.y, ww.z, ww.w, e1);
            float rv0 = s0l * wx[g][0] + s0h * wx[g][1];
            float rv1 = s1l * wx[g][2] + s1h * wx[g][3];
            rsum[rr] = rv0 + rv1;
        }
        acc[g] = wy[g][0] * rsum[0] + wy[g][1] * rsum[1]
               + wy[g][2] * rsum[2] + wy[g][3] * rsum[3];
    }

    // ---- staged store: 4 contiguous channels (tail quad stores 2) ----
    float* o = out + (size_t)k * PSR_C + cb;
    f2v a { acc[0], acc[1] };
    *(f2v*)o = a;
    if (cb + 4 <= PSR_C) {
        f2v c2 { acc[2], acc[3] };
        *(f2v*)(o + 2) = c2;
    }
}

extern "C" void kernel_launch(void* const* d_in, const int* in_sizes, int n_in,
                              void* d_out, int out_size, void* d_ws, size_t ws_size,
                              hipStream_t stream) {
    const float* input = (const float*)d_in[0];
    const float* rois  = (const float*)d_in[1];
    float* out = (float*)d_out;

    PSRoIAlign_72069551227028_kernel<<<1024, 256, 0, stream>>>(input, rois, out);
}